// Round 21
// baseline (383.863 us; speedup 1.0000x reference)
//
#include <hip/hip_runtime.h>
#include <hip/hip_bf16.h>
#include <cstdint>
#include <cstddef>

#define S_ 256
#define N_ 1024
#define H_ 512
#define AD_ 128
static constexpr int M_TOTAL = N_ * S_;

typedef __attribute__((ext_vector_type(8))) short short8;
typedef __attribute__((ext_vector_type(4))) float f32x4;

// raw barrier WITHOUT the __syncthreads vmcnt(0) drain: LDS visibility only.
#define LDS_BARRIER()                                       \
  asm volatile("s_waitcnt lgkmcnt(0)" ::: "memory");        \
  __builtin_amdgcn_s_barrier()

// 16-lane (DPP-row) sum via VALU-only rotation reduce (no LDS-pipe traffic).
__device__ __forceinline__ float red16_dpp(float v) {
  union fi { float f; int i; };
  fi a, r;
  a.f = v;
  r.i = __builtin_amdgcn_update_dpp(0, a.i, 0xB1, 0xF, 0xF, true);   // quad xor1
  a.f += r.f;
  r.i = __builtin_amdgcn_update_dpp(0, a.i, 0x4E, 0xF, 0xF, true);   // quad xor2
  a.f += r.f;
  r.i = __builtin_amdgcn_update_dpp(0, a.i, 0x124, 0xF, 0xF, true);  // row_ror:4
  a.f += r.f;
  r.i = __builtin_amdgcn_update_dpp(0, a.i, 0x128, 0xF, 0xF, true);  // row_ror:8
  a.f += r.f;
  return a.f;
}

// ---------------------------------------------------------------------------
// K0: W1 [H][AD] f32 -> MFMA-fragment-ordered bf16 (B-frag = linear 16B/lane).
// ---------------------------------------------------------------------------
__global__ __launch_bounds__(256) void k_w1frag(
    const float* __restrict__ w1_pre, const float* __restrict__ w1_fol,
    unsigned short* __restrict__ w1f) {
  int idx = blockIdx.x * 256 + threadIdx.x;  // 0..65535
  int st = blockIdx.y;
  const float* w1 = st ? w1_fol : w1_pre;
  int j = idx & 7;
  int lane = (idx >> 3) & 63;
  int c = (idx >> 9) & 7;
  int kk = idx >> 12;
  int k = kk * 32 + ((lane >> 4) << 3) + j;
  int d = c * 16 + (lane & 15);
  __hip_bfloat16 hb = __float2bfloat16(w1[(size_t)k * AD_ + d]);
  w1f[(size_t)st * 65536 + idx] = *(unsigned short*)&hb;
}

// ---------------------------------------------------------------------------
// K1: inclusive prefix sum of is_valid -> pos (rank-1), per stream.
// ---------------------------------------------------------------------------
__global__ __launch_bounds__(1024) void k_scan(
    const int* __restrict__ valid_pre, const int* __restrict__ valid_fol,
    int* __restrict__ pos) {
  const int st = blockIdx.x;
  const int* valid = st ? valid_fol : valid_pre;
  __shared__ int buf[1024];
  const int t = threadIdx.x;
  buf[t] = valid[t];
  __syncthreads();
  for (int off = 1; off < 1024; off <<= 1) {
    int v = (t >= off) ? buf[t - off] : 0;
    __syncthreads();
    buf[t] += v;
    __syncthreads();
  }
  pos[st * N_ + t] = buf[t] - 1;
}

// ---------------------------------------------------------------------------
// K2: FULLY FUSED per (stream, n): logits GEMM (pv2-shaped streaming, 16
// steps x 16 s-rows, XOR-swizzle, dual-acc, DPP epilogue, deferred reduce
// into LDS lgbuf) -> wave-0 dual softmax -> PV re-read of the SAME 512 KB
// tile (descending s, 8-deep batches) which is L3-resident: 256 co-resident
// blocks x 512 KB = 128 MB < 256 MB Infinity Cache. LDS padded >80 KB to
// force 1 block/CU (pad kept alive via opaque runtime condition).
// ---------------------------------------------------------------------------
__global__ __launch_bounds__(512) void k_fused(
    const float* __restrict__ emb_pre, const float* __restrict__ emb_fol,
    const unsigned short* __restrict__ w1f,
    const float* __restrict__ w2_pre, const float* __restrict__ w2_fol,
    const unsigned char* __restrict__ mask_pre, const unsigned char* __restrict__ mask_fol,
    float* __restrict__ part) {
  __shared__ __align__(16) unsigned char As[32768];   // 2 buf x 16 rows x 1KB
  __shared__ float partb[2][8][16][2];                // 4 KB
  __shared__ float lgbuf[S_][2];                      // 2 KB
  __shared__ float wl[S_];                            // 1 KB
  __shared__ __align__(16) float p3[4][128][4];       // 8 KB
  __shared__ float pad_[9216];                        // 36 KB -> 1 block/CU

  const int t = threadIdx.x;
  if (blockDim.y == 2) pad_[t] = 0.f;   // never true at runtime; keeps pad_

  const int bid = blockIdx.x;           // 0..2047
  const int st  = bid >> 10;
  const int n   = bid & 1023;
  const float* __restrict__ emb = st ? emb_fol : emb_pre;
  const float* __restrict__ w2  = st ? w2_fol : w2_pre;
  const unsigned char* __restrict__ mask = st ? mask_fol : mask_pre;

  const int w = t >> 6, lane = t & 63;
  const int r16 = lane & 15, kq = lane >> 4;

  // B: wave w's 16-col tile, all 16 K-chunks, register-resident (64 VGPR)
  short8 B[16];
  {
    const unsigned short* bb = w1f + (size_t)st * 65536 + w * 512 + (size_t)lane * 8;
#pragma unroll
    for (int kk = 0; kk < 16; ++kk) B[kk] = *(const short8*)(bb + kk * 4096);
  }
  const float w2v0 = w2[(w * 16 + r16) * 2 + 0];
  const float w2v1 = w2[(w * 16 + r16) * 2 + 1];

  // staging: wave w covers s = ms*16 + w (rows w) and +8 (rows w+8).
  // instr j: region (j>>1), byte-in-row cb = (j&1)*1024 + lane*16.
  const size_t SSTR = (size_t)N_ * H_;
  const float* baseA = emb + ((size_t)w * N_ + n) * H_;
  unsigned wadr[4];
#pragma unroll
  for (int j = 0; j < 4; ++j) {
    int cb = (j & 1) * 1024 + lane * 16;
    int R  = (j >> 1) * 8 + w;
    int g16 = cb >> 5, half = (cb >> 4) & 1;
    wadr[j] = (unsigned)(R * 1024 + ((g16 ^ (R & 7)) * 16) + half * 8);
  }

  float4 nxt[4];
#define LD_STEP(MS)                                                          \
  {                                                                          \
    _Pragma("unroll")                                                        \
    for (int j = 0; j < 4; ++j)                                              \
      nxt[j] = *(const float4*)(baseA + (size_t)(MS) * 16 * SSTR +           \
                                (size_t)(j >> 1) * 8 * SSTR +                \
                                (j & 1) * 256 + lane * 4);                   \
  }
#define ST_STEP(BUFB)                                                        \
  {                                                                          \
    _Pragma("unroll")                                                        \
    for (int j = 0; j < 4; ++j) {                                            \
      union { unsigned long long u; __hip_bfloat162 h[2]; } p;               \
      p.h[0] = __float22bfloat162_rn(make_float2(nxt[j].x, nxt[j].y));       \
      p.h[1] = __float22bfloat162_rn(make_float2(nxt[j].z, nxt[j].w));       \
      *(unsigned long long*)&As[(BUFB) + wadr[j]] = p.u;                     \
    }                                                                        \
  }

  // prologue: step 0 -> As[0]; preload step 1
  LD_STEP(0);
  ST_STEP(0);
  LD_STEP(1);
  LDS_BARRIER();

  for (int ss = 0; ss < 16; ++ss) {
    const int cur = ss & 1;
    const int nb  = cur ^ 1;
    const unsigned abase = (unsigned)(cur << 14);

    if (ss < 15) ST_STEP((unsigned)(nb << 14));
    if (ss < 14) LD_STEP(ss + 2);

    // deferred cross-wave reduce: logits for step ss-1 -> LDS lgbuf
    if (ss > 0 && lane < 4) {
      int vv = w * 4 + lane;
      int row = vv >> 1, rr = vv & 1;
      float v = 0.f;
#pragma unroll
      for (int g = 0; g < 8; ++g) v += partb[nb][g][row][rr];
      lgbuf[(ss - 1) * 16 + row][rr] = v;
    }

    // compute: 16 MFMAs, dual accumulators from As[cur]
    f32x4 a0 = (f32x4){0.f, 0.f, 0.f, 0.f};
    f32x4 a1 = (f32x4){0.f, 0.f, 0.f, 0.f};
#pragma unroll
    for (int kk = 0; kk < 16; ++kk) {
      const unsigned ra = abase +
          (unsigned)(r16 * 1024 + (((kk * 4 + kq) ^ (r16 & 7)) * 16));
      short8 a = *(const short8*)&As[ra];
      if (kk & 1)
        a1 = __builtin_amdgcn_mfma_f32_16x16x32_bf16(a, B[kk], a1, 0, 0, 0);
      else
        a0 = __builtin_amdgcn_mfma_f32_16x16x32_bf16(a, B[kk], a0, 0, 0, 0);
    }

    // epilogue: tanh (exp-form), @W2, DPP reduce -> partb[cur]
#pragma unroll
    for (int q = 0; q < 4; ++q) {
      float xc = fminf(fmaxf(a0[q] + a1[q], -10.f), 10.f);
      float e  = __expf(2.f * xc);
      float th = (e - 1.f) / (e + 1.f);
      float p0 = red16_dpp(th * w2v0);
      float p1 = red16_dpp(th * w2v1);
      if (r16 == 0) {
        partb[cur][w][kq * 4 + q][0] = p0;
        partb[cur][w][kq * 4 + q][1] = p1;
      }
    }
    LDS_BARRIER();
  }

  // tail: reduce step 15 (cur = 1)
  if (lane < 4) {
    int vv = w * 4 + lane;
    int row = vv >> 1, rr = vv & 1;
    float v = 0.f;
#pragma unroll
    for (int g = 0; g < 8; ++g) v += partb[1][g][row][rr];
    lgbuf[240 + row][rr] = v;
  }
  LDS_BARRIER();

  // ---- phase 2: dual softmax over all 256 s (wave 0, pure shfl)
  if (w == 0) {
    uchar4 mkb = *(const uchar4*)(mask + (size_t)n * S_ + lane * 4);
    float l0[4], l1[4];
    bool mk[4];
#pragma unroll
    for (int i = 0; i < 4; ++i) {
      l0[i] = lgbuf[lane * 4 + i][0];
      l1[i] = lgbuf[lane * 4 + i][1];
    }
    mk[0] = mkb.x != 0; mk[1] = mkb.y != 0; mk[2] = mkb.z != 0; mk[3] = mkb.w != 0;
    float q0[4], q1[4];
#pragma unroll
    for (int r = 0; r < 2; ++r) {
      float* lv = r ? l1 : l0;
      float* qq = r ? q1 : q0;
      float m1 = fmaxf(fmaxf(lv[0], lv[1]), fmaxf(lv[2], lv[3]));
#pragma unroll
      for (int off = 32; off; off >>= 1) m1 = fmaxf(m1, __shfl_xor(m1, off));
      float e[4], s1 = 0.f;
#pragma unroll
      for (int i = 0; i < 4; ++i) { e[i] = __expf(lv[i] - m1); s1 += e[i]; }
#pragma unroll
      for (int off = 32; off; off >>= 1) s1 += __shfl_xor(s1, off);
      float inv1 = 1.f / s1;
      float v[4];
#pragma unroll
      for (int i = 0; i < 4; ++i) v[i] = mk[i] ? -INFINITY : e[i] * inv1;
      float m2 = fmaxf(fmaxf(v[0], v[1]), fmaxf(v[2], v[3]));
#pragma unroll
      for (int off = 32; off; off >>= 1) m2 = fmaxf(m2, __shfl_xor(m2, off));
      float e2[4], s2 = 0.f;
#pragma unroll
      for (int i = 0; i < 4; ++i) { e2[i] = mk[i] ? 0.f : __expf(v[i] - m2); s2 += e2[i]; }
#pragma unroll
      for (int off = 32; off; off >>= 1) s2 += __shfl_xor(s2, off);
      float inv2 = 1.f / s2;
#pragma unroll
      for (int i = 0; i < 4; ++i) qq[i] = e2[i] * inv2;
    }
#pragma unroll
    for (int i = 0; i < 4; ++i) wl[lane * 4 + i] = 0.5f * (q0[i] + q1[i]);
  }
  LDS_BARRIER();

  // ---- phase 3: PV re-read of the L3-resident tile. 4 s-quarters x 128
  // h-threads; descending s within quarter; 8 loads in flight per thread.
  {
    const int sg = t >> 7, tt = t & 127, c0 = tt * 4;
    const float* embn = emb + (size_t)n * H_ + c0;
    float4 acc = (float4){0.f, 0.f, 0.f, 0.f};
    const int sTop = sg * 64 + 63;
#pragma unroll
    for (int b2 = 0; b2 < 8; ++b2) {
      const int sb = sTop - b2 * 8;
      float4 x[8];
#pragma unroll
      for (int i = 0; i < 8; ++i)
        x[i] = *(const float4*)(embn + (size_t)(sb - i) * SSTR);
#pragma unroll
      for (int i = 0; i < 8; ++i) {
        const float wv = wl[sb - i];
        acc.x += wv * x[i].x;
        acc.y += wv * x[i].y;
        acc.z += wv * x[i].z;
        acc.w += wv * x[i].w;
      }
    }
    *(float4*)&p3[sg][tt][0] = acc;
  }
  LDS_BARRIER();
  if (t < 128) {
    float4 r;
    r.x = p3[0][t][0] + p3[1][t][0] + p3[2][t][0] + p3[3][t][0];
    r.y = p3[0][t][1] + p3[1][t][1] + p3[2][t][1] + p3[3][t][1];
    r.z = p3[0][t][2] + p3[1][t][2] + p3[2][t][2] + p3[3][t][2];
    r.w = p3[0][t][3] + p3[1][t][3] + p3[2][t][3] + p3[3][t][3];
    *(float4*)&part[((size_t)st * N_ + n) * H_ + t * 4] = r;
  }
}

// ---------------------------------------------------------------------------
// K5: valid/pos gather -> out[n][st*512 + h].
// ---------------------------------------------------------------------------
__global__ __launch_bounds__(256) void k_combine(
    const float* __restrict__ part, const int* __restrict__ pos,
    const int* __restrict__ valid_pre, const int* __restrict__ valid_fol,
    float* __restrict__ out) {
  const int n = blockIdx.x, t = threadIdx.x;
  const int st = t >> 7;
  const int c = (t & 127) * 4;
  const int* valid = st ? valid_fol : valid_pre;
  float4 r = {0.f, 0.f, 0.f, 0.f};
  if (valid[n] > 0) {
    int np = pos[st * N_ + n]; if (np < 0) np = 0;
    r = *(const float4*)&part[((size_t)st * N_ + np) * H_ + c];
  }
  *(float4*)&out[(size_t)n * 1024 + st * 512 + c] = r;
}

// ---------------------------------------------------------------------------
extern "C" void kernel_launch(void* const* d_in, const int* in_sizes, int n_in,
                              void* d_out, int out_size, void* d_ws, size_t ws_size,
                              hipStream_t stream) {
  const float* emb_pre = (const float*)d_in[0];
  const float* emb_fol = (const float*)d_in[1];
  const unsigned char* mask_pre = (const unsigned char*)d_in[2];
  const unsigned char* mask_fol = (const unsigned char*)d_in[3];
  const int* valid_pre = (const int*)d_in[4];
  const int* valid_fol = (const int*)d_in[5];
  const float* w1_pre = (const float*)d_in[6];
  const float* w2_pre = (const float*)d_in[7];
  const float* w1_fol = (const float*)d_in[8];
  const float* w2_fol = (const float*)d_in[9];
  float* out = (float*)d_out;

  char* ws = (char*)d_ws;
  unsigned short* w1f = (unsigned short*)ws;                    // 256 KiB
  int*   pos    = (int*)(ws + 262144);                          // 8 KiB
  float* part   = (float*)(ws + 270336);                        // 4 MiB [2][N][H]

  hipLaunchKernelGGL(k_w1frag, dim3(256, 2), dim3(256), 0, stream,
                     w1_pre, w1_fol, w1f);
  hipLaunchKernelGGL(k_scan, dim3(2), dim3(1024), 0, stream,
                     valid_pre, valid_fol, pos);
  hipLaunchKernelGGL(k_fused, dim3(2048), dim3(512), 0, stream,
                     emb_pre, emb_fol, w1f, w2_pre, w2_fol,
                     mask_pre, mask_fol, part);
  hipLaunchKernelGGL(k_combine, dim3(N_), dim3(256), 0, stream,
                     part, pos, valid_pre, valid_fol, out);
}